// Round 12
// baseline (447.899 us; speedup 1.0000x reference)
//
#include <hip/hip_runtime.h>
#include <hip/hip_bf16.h>

// ---------------------------------------------------------------------------
// GraphSAGE x3 (mean aggr, ReLU) + 3 fused heads.  N=50000, E=800000.
// R11 (resubmitted after infra timeout): agg + MFMA GEMM fused into one
// kernel per layer (dependency is row-local: mfma(node) needs only
// mean(node)).  Gather means into LDS (same summation order as R10 ->
// bit-identical numerics), then MFMA with mean chunks from LDS.
// h ping-pongs h0/h1 (in-place would race gathers).  10 dispatches.
// ---------------------------------------------------------------------------

typedef __attribute__((ext_vector_type(8))) short bf16x8;
typedef __attribute__((ext_vector_type(4))) float f32x4;

#define NBSH 7          // 128 nodes per bucket
#define EPW  4096       // edges per sort chunk

__device__ __forceinline__ unsigned short f2b(float f) {
    __hip_bfloat16 h = __float2bfloat16(f);
    return *reinterpret_cast<unsigned short*>(&h);
}
__device__ __forceinline__ float b2f(unsigned short u) {
    __hip_bfloat16 h;
    *reinterpret_cast<unsigned short*>(&h) = u;
    return __bfloat162float(h);
}

// ---------------- bucketed CSR build ----------------
__global__ void bucket_hist(const int* __restrict__ dst, int* __restrict__ ghist,
                            int n_edges, int nb) {
    __shared__ int lh[512];
    int tid = threadIdx.x;
    for (int i = tid; i < 512; i += 256) lh[i] = 0;
    __syncthreads();
    int stride = gridDim.x * blockDim.x;
    for (int e = blockIdx.x * blockDim.x + tid; e < n_edges; e += stride)
        atomicAdd(&lh[dst[e] >> NBSH], 1);
    __syncthreads();
    for (int i = tid; i < nb; i += 256)
        if (lh[i]) atomicAdd(&ghist[i], lh[i]);
}

__global__ void scan_buckets(const int* __restrict__ hist, int* __restrict__ base,
                             int* __restrict__ cur, int nb, int n_edges) {
    __shared__ int tmp[512];
    int t = threadIdx.x;
    int v = (t < nb) ? hist[t] : 0;
    tmp[t] = v;
    __syncthreads();
    for (int off = 1; off < 512; off <<= 1) {
        int u = (t >= off) ? tmp[t - off] : 0;
        __syncthreads();
        tmp[t] += u;
        __syncthreads();
    }
    if (t < nb) {
        base[t] = tmp[t] - v;
        cur[t] = tmp[t] - v;
    }
    if (t == 0) base[nb] = n_edges;
}

__global__ __launch_bounds__(512) void bin_edges_lds(
    const int* __restrict__ src, const int* __restrict__ dst,
    int* __restrict__ bkt_cur, uint2* __restrict__ ebuf, int n_edges, int nb) {
    __shared__ int hist[512];
    __shared__ int hbase[513];
    __shared__ int hcur[512];
    __shared__ uint2 sorted[EPW];
    int tid = threadIdx.x;
    int chunk0 = blockIdx.x * EPW;
    int cnt = min(EPW, n_edges - chunk0);
    hist[tid] = 0;
    __syncthreads();
    for (int i = tid; i < cnt; i += 512) atomicAdd(&hist[dst[chunk0 + i] >> NBSH], 1);
    __syncthreads();
    int v = hist[tid];
    hbase[tid] = v;
    __syncthreads();
    for (int off = 1; off < 512; off <<= 1) {
        int u = (tid >= off) ? hbase[tid - off] : 0;
        __syncthreads();
        hbase[tid] += u;
        __syncthreads();
    }
    int excl = hbase[tid] - v;
    __syncthreads();
    hbase[tid] = excl;
    hcur[tid] = excl;
    if (tid == 511) hbase[512] = excl + v;
    __syncthreads();
    for (int i = tid; i < cnt; i += 512) {
        int s = src[chunk0 + i];
        int d = dst[chunk0 + i];
        int p = atomicAdd(&hcur[d >> NBSH], 1);
        sorted[p] = make_uint2((unsigned)s, (unsigned)d);
    }
    __syncthreads();
    int cntb = hbase[tid + 1] - hbase[tid];
    int gb = 0;
    if (tid < nb && cntb > 0) gb = atomicAdd(&bkt_cur[tid], cntb);
    hist[tid] = gb;
    __syncthreads();
    for (int i = tid; i < cnt; i += 512) {
        uint2 ed = sorted[i];
        int b = (int)(ed.y >> NBSH);
        ebuf[hist[b] + (i - hbase[b])] = ed;
    }
}

// Fused: per-bucket degree count + local scan -> row_start + LDS-cursor scatter.
__global__ void sort_bucket(const uint2* __restrict__ ebuf, const int* __restrict__ bkt_base,
                            int* __restrict__ row_start, int* __restrict__ col,
                            int n_nodes, int n_edges) {
    __shared__ int hist[128];
    __shared__ int sc[128];
    __shared__ int hcur[128];
    int b = blockIdx.x, tid = threadIdx.x;
    int lo = b << NBSH;
    if (tid < 128) hist[tid] = 0;
    __syncthreads();
    int s = bkt_base[b], t = bkt_base[b + 1];
    for (int i = s + tid; i < t; i += 256) atomicAdd(&hist[(int)ebuf[i].y - lo], 1);
    __syncthreads();
    if (tid < 128) sc[tid] = hist[tid];
    __syncthreads();
    for (int off = 1; off < 128; off <<= 1) {
        int u = (tid < 128 && tid >= off) ? sc[tid - off] : 0;
        __syncthreads();
        if (tid < 128) sc[tid] += u;
        __syncthreads();
    }
    if (tid < 128) {
        int excl = sc[tid] - hist[tid];
        hcur[tid] = excl;
        int node = lo + tid;
        if (node < n_nodes) row_start[node] = s + excl;
    }
    if (b == 0 && tid == 0) row_start[n_nodes] = n_edges;
    __syncthreads();
    for (int i = s + tid; i < t; i += 256) {
        uint2 ed = ebuf[i];
        int p = atomicAdd(&hcur[(int)ed.y - lo], 1);
        col[s + p] = (int)ed.x;
    }
}

// ---------------- fused prep: convert_x + 3x build_bt + cat + zero hist ----
__device__ __forceinline__ void bt_body(const float* __restrict__ Wl,
                                        const float* __restrict__ Wr,
                                        unsigned short* __restrict__ Bt,
                                        int KA, int idx) {
    int KTOT = 2 * KA;
    if (idx >= 128 * KTOT) return;
    int n = idx / KTOT, k = idx % KTOT;
    float v = (k < KA) ? Wl[k * 128 + n] : Wr[(k - KA) * 128 + n];
    Bt[idx] = f2b(v);
}

__global__ void prep_all(const float* __restrict__ x, unsigned short* __restrict__ xb, int n4,
                         const float* __restrict__ Wl1, const float* __restrict__ Wr1,
                         unsigned short* __restrict__ Bt1,
                         const float* __restrict__ Wl2, const float* __restrict__ Wr2,
                         unsigned short* __restrict__ Bt2,
                         const float* __restrict__ Wl3, const float* __restrict__ Wr3,
                         unsigned short* __restrict__ Bt3,
                         const float* __restrict__ Wl_age, const float* __restrict__ Wl_sex,
                         const float* __restrict__ Wl_eth,
                         const float* __restrict__ Wr_age, const float* __restrict__ Wr_sex,
                         const float* __restrict__ Wr_eth,
                         const float* __restrict__ b_age, const float* __restrict__ b_sex,
                         const float* __restrict__ b_eth,
                         float* __restrict__ Wl_cat, float* __restrict__ Wr_cat,
                         float* __restrict__ b_cat, int* __restrict__ bkt_hist) {
    int nbx = (n4 + 255) / 256;       // convert_x blocks
    int b = blockIdx.x;
    if (b < nbx) {
        int t = b * 256 + threadIdx.x;
        if (t < n4) {
            float4 v = reinterpret_cast<const float4*>(x)[t];
            uint2 o;
            o.x = (unsigned)f2b(v.x) | ((unsigned)f2b(v.y) << 16);
            o.y = (unsigned)f2b(v.z) | ((unsigned)f2b(v.w) << 16);
            reinterpret_cast<uint2*>(xb)[t] = o;
        }
        return;
    }
    b -= nbx;
    if (b < 64)  { bt_body(Wl1, Wr1, Bt1, 64,  b * 256 + threadIdx.x); return; }
    b -= 64;
    if (b < 128) { bt_body(Wl2, Wr2, Bt2, 128, b * 256 + threadIdx.x); return; }
    b -= 128;
    if (b < 128) { bt_body(Wl3, Wr3, Bt3, 128, b * 256 + threadIdx.x); return; }
    b -= 128;
    if (b < 14) {   // cat: 14 blocks cover 128*28
        int idx = b * 256 + threadIdx.x;
        if (idx < 128 * 28) {
            int k = idx / 28, j = idx % 28;
            float vl, vr;
            if (j < 21) {
                vl = Wl_age[k * 21 + j];
                vr = Wr_age[k * 21 + j];
            } else if (j < 23) {
                vl = Wl_sex[k * 2 + (j - 21)];
                vr = Wr_sex[k * 2 + (j - 21)];
            } else {
                vl = Wl_eth[k * 5 + (j - 23)];
                vr = Wr_eth[k * 5 + (j - 23)];
            }
            Wl_cat[idx] = vl;
            Wr_cat[idx] = vr;
        }
        if (idx < 28)
            b_cat[idx] = (idx < 21) ? b_age[idx] : (idx < 23) ? b_sex[idx - 21] : b_eth[idx - 23];
        return;
    }
    // final block: zero the 512-int bucket histogram
    bkt_hist[threadIdx.x] = 0;
    bkt_hist[256 + threadIdx.x] = 0;
}

// ---------------- fused agg + MFMA layer ----------------
// out[i][j] = relu( [mean(feat)_i | feat_i](KTOT) . Bt[j] + bias[j] )
// Phase 1: each wave gathers means for its 16 nodes into LDS (bf16, same
// summation structure as R10's agg kernels -> identical rounding).
// Phase 2: MFMA; mean chunks (kc*64 < KA) read A-fragments from sMean LDS,
// feat chunks staged from global as before.
template <int KTOT, int KA>
__global__ __launch_bounds__(256) void layer_fused(
    const unsigned short* __restrict__ feat,
    const int* __restrict__ row_start, const int* __restrict__ col,
    const unsigned short* __restrict__ Bt, const float* __restrict__ bias,
    unsigned short* __restrict__ out, int n_nodes) {
    constexpr int KC = KTOT / 64;
    __shared__ __align__(16) unsigned short sA[64][72];
    __shared__ __align__(16) unsigned short sB[128][72];
    __shared__ __align__(16) unsigned short sMean[64][KA + 8];   // +8 pad
    int node0 = blockIdx.x * 64;
    int tid = threadIdx.x;
    int w = tid >> 6, lane = tid & 63;
    const unsigned* f2 = reinterpret_cast<const unsigned*>(feat);

    // ---- Phase 1: gather means (wave w -> nodes node0+w*16 .. +15) ----
    for (int nd = 0; nd < 16; ++nd) {
        int node = node0 + w * 16 + nd;
        if (node >= n_nodes) break;          // wave-uniform
        int s0 = row_start[node];
        int deg = row_start[node + 1] - s0;
        unsigned* mrow = reinterpret_cast<unsigned*>(&sMean[w * 16 + nd][0]);
        if (KA == 128) {
            float a0 = 0.f, a1 = 0.f, b0 = 0.f, b1 = 0.f;
            float c0 = 0.f, c1 = 0.f, d0 = 0.f, d1 = 0.f;
            for (int base = 0; base < deg; base += 64) {
                int blk = min(64, deg - base);
                int cv = col[s0 + base + min(lane, blk - 1)];
                int i = 0;
                for (; i + 3 < blk; i += 4) {
                    int e0 = __shfl(cv, i), e1 = __shfl(cv, i + 1);
                    int e2 = __shfl(cv, i + 2), e3 = __shfl(cv, i + 3);
                    unsigned u0 = f2[(size_t)e0 * 64 + lane];
                    unsigned u1 = f2[(size_t)e1 * 64 + lane];
                    unsigned u2 = f2[(size_t)e2 * 64 + lane];
                    unsigned u3 = f2[(size_t)e3 * 64 + lane];
                    a0 += b2f((unsigned short)(u0 & 0xffff)); a1 += b2f((unsigned short)(u0 >> 16));
                    b0 += b2f((unsigned short)(u1 & 0xffff)); b1 += b2f((unsigned short)(u1 >> 16));
                    c0 += b2f((unsigned short)(u2 & 0xffff)); c1 += b2f((unsigned short)(u2 >> 16));
                    d0 += b2f((unsigned short)(u3 & 0xffff)); d1 += b2f((unsigned short)(u3 >> 16));
                }
                for (; i < blk; ++i) {
                    int e0 = __shfl(cv, i);
                    unsigned u0 = f2[(size_t)e0 * 64 + lane];
                    a0 += b2f((unsigned short)(u0 & 0xffff)); a1 += b2f((unsigned short)(u0 >> 16));
                }
            }
            float inv = (deg > 0) ? 1.0f / (float)deg : 0.0f;
            float sAc = (a0 + b0) + (c0 + d0);
            float sBc = (a1 + b1) + (c1 + d1);
            mrow[lane] = (unsigned)f2b(sAc * inv) | ((unsigned)f2b(sBc * inv) << 16);
        } else {   // KA == 64: half-wave split (agg64 structure)
            int half = lane >> 5;
            int lp = lane & 31;
            float a0 = 0.f, a1 = 0.f, b0 = 0.f, b1 = 0.f;
            float c0 = 0.f, c1 = 0.f, d0 = 0.f, d1 = 0.f;
            for (int base = 0; base < deg; base += 64) {
                int blk = min(64, deg - base);
                int cv = col[s0 + base + min(lane, blk - 1)];
                int nfull = blk & ~7;
                for (int i = half * 4; i < nfull; i += 8) {
                    int e0 = __shfl(cv, i), e1 = __shfl(cv, i + 1);
                    int e2 = __shfl(cv, i + 2), e3 = __shfl(cv, i + 3);
                    unsigned u0 = f2[(size_t)e0 * 32 + lp];
                    unsigned u1 = f2[(size_t)e1 * 32 + lp];
                    unsigned u2 = f2[(size_t)e2 * 32 + lp];
                    unsigned u3 = f2[(size_t)e3 * 32 + lp];
                    a0 += b2f((unsigned short)(u0 & 0xffff)); a1 += b2f((unsigned short)(u0 >> 16));
                    b0 += b2f((unsigned short)(u1 & 0xffff)); b1 += b2f((unsigned short)(u1 >> 16));
                    c0 += b2f((unsigned short)(u2 & 0xffff)); c1 += b2f((unsigned short)(u2 >> 16));
                    d0 += b2f((unsigned short)(u3 & 0xffff)); d1 += b2f((unsigned short)(u3 >> 16));
                }
                int tstart = nfull + half * 4;
                int tend = min(blk, tstart + 4);
                for (int i = tstart; i < tend; ++i) {
                    int e0 = __shfl(cv, i);
                    unsigned u0 = f2[(size_t)e0 * 32 + lp];
                    a0 += b2f((unsigned short)(u0 & 0xffff)); a1 += b2f((unsigned short)(u0 >> 16));
                }
            }
            float sAc = (a0 + b0) + (c0 + d0);
            float sBc = (a1 + b1) + (c1 + d1);
            sAc += __shfl_down(sAc, 32);
            sBc += __shfl_down(sBc, 32);
            if (half == 0) {
                float inv = (deg > 0) ? 1.0f / (float)deg : 0.0f;
                mrow[lp] = (unsigned)f2b(sAc * inv) | ((unsigned)f2b(sBc * inv) << 16);
            }
        }
    }
    __syncthreads();

    // ---- Phase 2: MFMA ----
    f32x4 acc[8] = {};
    for (int kc = 0; kc < KC; ++kc) {
        bool from_mean = (kc * 64 < KA);
        if (!from_mean) {   // stage feat chunk into sA
            constexpr int AW = KTOT - KA;   // feat row width (bf16)
            int kbase = kc * 64 - KA;
            int nd = tid >> 2, k16 = (tid & 3) * 16;
            uint4 v0 = {0, 0, 0, 0}, v1 = {0, 0, 0, 0};
            int gn = node0 + nd;
            if (gn < n_nodes) {
                const uint4* src = reinterpret_cast<const uint4*>(feat + (size_t)gn * AW + kbase + k16);
                v0 = src[0];
                v1 = src[1];
            }
            uint4* dst = reinterpret_cast<uint4*>(&sA[nd][k16]);
            dst[0] = v0;
            dst[1] = v1;
        }
        {   // stage B chunk
            int n = tid >> 1, k32 = (tid & 1) * 32;
            const uint4* src = reinterpret_cast<const uint4*>(Bt + (size_t)n * KTOT + kc * 64 + k32);
            uint4* dst = reinterpret_cast<uint4*>(&sB[n][k32]);
            dst[0] = src[0];
            dst[1] = src[1];
            dst[2] = src[2];
            dst[3] = src[3];
        }
        __syncthreads();
#pragma unroll
        for (int ks = 0; ks < 2; ++ks) {
            int kl = ks * 32 + (lane >> 4) * 8;
            bf16x8 af;
            if (from_mean)
                af = *reinterpret_cast<const bf16x8*>(&sMean[w * 16 + (lane & 15)][kc * 64 + kl]);
            else
                af = *reinterpret_cast<const bf16x8*>(&sA[w * 16 + (lane & 15)][kl]);
#pragma unroll
            for (int t = 0; t < 8; ++t) {
                bf16x8 bfr = *reinterpret_cast<const bf16x8*>(&sB[t * 16 + (lane & 15)][kl]);
                acc[t] = __builtin_amdgcn_mfma_f32_16x16x32_bf16(af, bfr, acc[t], 0, 0, 0);
            }
        }
        __syncthreads();
    }
    // ---- epilogue: C/D map col=lane&15, row=(lane>>4)*4+i ----
    int r0 = w * 16, cq = lane >> 4, cr = lane & 15;
#pragma unroll
    for (int t = 0; t < 8; ++t) {
        int colj = t * 16 + cr;
        float bv = bias[colj];
#pragma unroll
        for (int i = 0; i < 4; ++i) {
            int node = node0 + r0 + cq * 4 + i;
            if (node < n_nodes) {
                float v = fmaxf(acc[t][i] + bv, 0.0f);
                out[(size_t)node * 128 + colj] = f2b(v);
            }
        }
    }
}

// ---------------- heads ----------------
// R10 register-blocked LDS GEMM: p = h@Wl, q = h@Wr + b (fp32).
__global__ __launch_bounds__(256) void proj2_kernel(
    const unsigned short* __restrict__ h,
    const float* __restrict__ Wl_cat, const float* __restrict__ Wr_cat,
    const float* __restrict__ b_cat,
    float* __restrict__ p, float* __restrict__ q, int n_nodes) {
    __shared__ float sh[64][128];        // 32 KB
    __shared__ float swl[128 * 28];      // 14 KB
    __shared__ float swr[128 * 28];      // 14 KB
    int node0 = blockIdx.x * 64;
    int tid = threadIdx.x;
    for (int i = tid; i < 128 * 28; i += 256) {
        swl[i] = Wl_cat[i];
        swr[i] = Wr_cat[i];
    }
    for (int it = tid; it < 1024; it += 256) {
        int n = it >> 4, k8 = (it & 15) * 8;
        int node = node0 + n;
        if (node < n_nodes) {
            uint4 u = *reinterpret_cast<const uint4*>(h + (size_t)node * 128 + k8);
            sh[n][k8 + 0] = b2f((unsigned short)(u.x & 0xffff));
            sh[n][k8 + 1] = b2f((unsigned short)(u.x >> 16));
            sh[n][k8 + 2] = b2f((unsigned short)(u.y & 0xffff));
            sh[n][k8 + 3] = b2f((unsigned short)(u.y >> 16));
            sh[n][k8 + 4] = b2f((unsigned short)(u.z & 0xffff));
            sh[n][k8 + 5] = b2f((unsigned short)(u.z >> 16));
            sh[n][k8 + 6] = b2f((unsigned short)(u.w & 0xffff));
            sh[n][k8 + 7] = b2f((unsigned short)(u.w >> 16));
        } else {
            for (int z = 0; z < 8; ++z) sh[n][k8 + z] = 0.f;
        }
    }
    __syncthreads();
    int j = tid & 31, ng = tid >> 5;
    float accp[8] = {};
    float accq[8] = {};
    if (j < 28) {
        for (int k = 0; k < 128; k += 2) {
            float wl0 = swl[k * 28 + j],       wr0 = swr[k * 28 + j];
            float wl1 = swl[(k + 1) * 28 + j], wr1 = swr[(k + 1) * 28 + j];
#pragma unroll
            for (int i = 0; i < 8; ++i) {
                float2 hv = *reinterpret_cast<const float2*>(&sh[ng * 8 + i][k]);
                accp[i] += hv.x * wl0 + hv.y * wl1;
                accq[i] += hv.x * wr0 + hv.y * wr1;
            }
        }
    }
    float bj = (j < 28) ? b_cat[j] : 0.f;
#pragma unroll
    for (int i = 0; i < 8; ++i) {
        int node = node0 + ng * 8 + i;
        if (node < n_nodes) {
            p[(size_t)node * 32 + j] = (j < 28) ? accp[i] : 0.f;
            q[(size_t)node * 32 + j] = (j < 28) ? (accq[i] + bj) : 0.f;
        }
    }
}

// 32-lane group per node: gather-mean of p + q[node] -> scatter to outputs.
__global__ void head_final(const float* __restrict__ p, const float* __restrict__ q,
                           const int* __restrict__ row_start, const int* __restrict__ col,
                           float* __restrict__ age, float* __restrict__ sex,
                           float* __restrict__ eth, int n_nodes) {
    int node = (blockIdx.x * blockDim.x + threadIdx.x) >> 5;
    int lane = threadIdx.x & 63;
    int lp = lane & 31;
    int grpbase = lane & 32;
    if (node >= n_nodes) return;
    int s0 = row_start[node];
    int deg = row_start[node + 1] - s0;
    float a = 0.f, b = 0.f, c = 0.f, d = 0.f;
    for (int base = 0; base < deg; base += 32) {
        int blk = min(32, deg - base);
        int cv = col[s0 + base + min(lp, blk - 1)];
        int i = 0;
        for (; i + 3 < blk; i += 4) {
            int e0 = __shfl(cv, grpbase + i),     e1 = __shfl(cv, grpbase + i + 1);
            int e2 = __shfl(cv, grpbase + i + 2), e3 = __shfl(cv, grpbase + i + 3);
            a += p[(size_t)e0 * 32 + lp];
            b += p[(size_t)e1 * 32 + lp];
            c += p[(size_t)e2 * 32 + lp];
            d += p[(size_t)e3 * 32 + lp];
        }
        for (; i < blk; ++i) {
            int e0 = __shfl(cv, grpbase + i);
            a += p[(size_t)e0 * 32 + lp];
        }
    }
    float inv = (deg > 0) ? 1.0f / (float)deg : 0.0f;
    float out = ((a + b) + (c + d)) * inv + q[(size_t)node * 32 + lp];
    if (lp < 21)
        age[(size_t)node * 21 + lp] = out;
    else if (lp < 23)
        sex[(size_t)node * 2 + (lp - 21)] = out;
    else if (lp < 28)
        eth[(size_t)node * 5 + (lp - 23)] = out;
}

extern "C" void kernel_launch(void* const* d_in, const int* in_sizes, int n_in,
                              void* d_out, int out_size, void* d_ws, size_t ws_size,
                              hipStream_t stream) {
    const float* x        = (const float*)d_in[0];
    const int*   edge_src = (const int*)d_in[1];
    const int*   edge_dst = (const int*)d_in[2];
    const float* Wl_1 = (const float*)d_in[3];
    const float* Wr_1 = (const float*)d_in[4];
    const float* b_1  = (const float*)d_in[5];
    const float* Wl_2 = (const float*)d_in[6];
    const float* Wr_2 = (const float*)d_in[7];
    const float* b_2  = (const float*)d_in[8];
    const float* Wl_3 = (const float*)d_in[9];
    const float* Wr_3 = (const float*)d_in[10];
    const float* b_3  = (const float*)d_in[11];
    const float* Wl_age = (const float*)d_in[12];
    const float* Wr_age = (const float*)d_in[13];
    const float* b_age  = (const float*)d_in[14];
    const float* Wl_sex = (const float*)d_in[15];
    const float* Wr_sex = (const float*)d_in[16];
    const float* b_sex  = (const float*)d_in[17];
    const float* Wl_eth = (const float*)d_in[18];
    const float* Wr_eth = (const float*)d_in[19];
    const float* b_eth  = (const float*)d_in[20];

    const int n_nodes = in_sizes[0] / 64;   // 50000
    const int n_edges = in_sizes[1];        // 800000

    // ---- workspace layout ----
    char* ws = (char*)d_ws;
    int*            row_start = (int*)(ws + 200192);             // 200192
    int*            col       = (int*)(ws + 600576);             // 3200256
    unsigned short* Bt1       = (unsigned short*)(ws + 3800832); // 32768
    unsigned short* Bt2       = (unsigned short*)(ws + 3833600); // 65536
    unsigned short* Bt3       = (unsigned short*)(ws + 3899136); // 65536
    float*          Wl_cat    = (float*)(ws + 3964672);          // 14336
    float*          Wr_cat    = (float*)(ws + 3979008);          // 14336
    float*          b_cat     = (float*)(ws + 3993344);          // 256
    unsigned short* xb        = (unsigned short*)(ws + 3993600); // 6400256
    unsigned short* h0        = (unsigned short*)(ws + 10393856);// 12800256
    unsigned short* h1        = (unsigned short*)(ws + 23194112);// 12800256
    float*          p         = (float*)(ws + 35994368);         // 6400256  (head phase)
    float*          q         = (float*)(ws + 42394624);         // 6400256  (head phase)
    // CSR-build-phase aliases (p / q not live yet):
    uint2*          ebuf      = (uint2*)p;                       // 6.4 MB
    int*            bkt_hist  = (int*)q;                         // 512 ints
    int*            bkt_base  = bkt_hist + 512;                  // 513 ints
    int*            bkt_cur   = bkt_hist + 1032;                 // 512 ints

    float* out_age = (float*)d_out;
    float* out_sex = out_age + (size_t)n_nodes * 21;
    float* out_eth = out_sex + (size_t)n_nodes * 2;

    const int nb      = (n_nodes + 127) >> NBSH;          // 391 buckets
    const int nchunks = (n_edges + EPW - 1) / EPW;        // 196
    const int n4      = n_nodes * 64 / 4;                 // 800000

    // ---- fused prep (convert_x + Bt1..3 + cat + zero bkt_hist) ----
    {
        int grid = (n4 + 255) / 256 + 64 + 128 + 128 + 14 + 1;
        prep_all<<<grid, 256, 0, stream>>>(
            x, xb, n4, Wl_1, Wr_1, Bt1, Wl_2, Wr_2, Bt2, Wl_3, Wr_3, Bt3,
            Wl_age, Wl_sex, Wl_eth, Wr_age, Wr_sex, Wr_eth, b_age, b_sex, b_eth,
            Wl_cat, Wr_cat, b_cat, bkt_hist);
    }

    // ---- CSR build (bucketed, locality-aware) ----
    bucket_hist<<<256, 256, 0, stream>>>(edge_dst, bkt_hist, n_edges, nb);
    scan_buckets<<<1, 512, 0, stream>>>(bkt_hist, bkt_base, bkt_cur, nb, n_edges);
    bin_edges_lds<<<nchunks, 512, 0, stream>>>(edge_src, edge_dst, bkt_cur, ebuf, n_edges, nb);
    sort_bucket<<<nb, 256, 0, stream>>>(ebuf, bkt_base, row_start, col, n_nodes, n_edges);

    const int gemm_grid = (n_nodes + 63) / 64;

    // ---- Layers (fused gather+GEMM, h ping-pong) ----
    layer_fused<128, 64><<<gemm_grid, 256, 0, stream>>>(xb, row_start, col, Bt1, b_1, h0, n_nodes);
    layer_fused<256, 128><<<gemm_grid, 256, 0, stream>>>(h0, row_start, col, Bt2, b_2, h1, n_nodes);
    layer_fused<256, 128><<<gemm_grid, 256, 0, stream>>>(h1, row_start, col, Bt3, b_3, h0, n_nodes);

    // ---- Heads: p = h@Wl, q = h@Wr+b, then mean(p)+q -> scatter ----
    proj2_kernel<<<(n_nodes + 63) / 64, 256, 0, stream>>>(h0, Wl_cat, Wr_cat, b_cat, p, q, n_nodes);
    head_final<<<(n_nodes * 32 + 255) / 256, 256, 0, stream>>>(
        p, q, row_start, col, out_age, out_sex, out_eth, n_nodes);
}

// Round 14
// 314.114 us; speedup vs baseline: 1.4259x; 1.4259x over previous
//
#include <hip/hip_runtime.h>
#include <hip/hip_bf16.h>

// ---------------------------------------------------------------------------
// GraphSAGE x3 (mean aggr, ReLU) + 3 fused heads.  N=50000, E=800000.
// R13 (resubmitted after infra timeout): REVERT of R11/R12 fusion
// (layer_fused was 107us vs 55us for the separate pair: gather lost 16x
// TLP + L2 locality, occupancy capped by 44KB LDS).  Back to R10 structure
// (316us measured), plus one safe delta: bucket_hist folded into prep_all
// (zeroing via 2KB memset before it).
// ---------------------------------------------------------------------------

typedef __attribute__((ext_vector_type(8))) short bf16x8;
typedef __attribute__((ext_vector_type(4))) float f32x4;

#define NBSH 7          // 128 nodes per bucket
#define EPW  4096       // edges per sort chunk

__device__ __forceinline__ unsigned short f2b(float f) {
    __hip_bfloat16 h = __float2bfloat16(f);
    return *reinterpret_cast<unsigned short*>(&h);
}
__device__ __forceinline__ float b2f(unsigned short u) {
    __hip_bfloat16 h;
    *reinterpret_cast<unsigned short*>(&h) = u;
    return __bfloat162float(h);
}

// ---------------- bucketed CSR build ----------------
__global__ void scan_buckets(const int* __restrict__ hist, int* __restrict__ base,
                             int* __restrict__ cur, int nb, int n_edges) {
    __shared__ int tmp[512];
    int t = threadIdx.x;
    int v = (t < nb) ? hist[t] : 0;
    tmp[t] = v;
    __syncthreads();
    for (int off = 1; off < 512; off <<= 1) {
        int u = (t >= off) ? tmp[t - off] : 0;
        __syncthreads();
        tmp[t] += u;
        __syncthreads();
    }
    if (t < nb) {
        base[t] = tmp[t] - v;
        cur[t] = tmp[t] - v;
    }
    if (t == 0) base[nb] = n_edges;
}

__global__ __launch_bounds__(512) void bin_edges_lds(
    const int* __restrict__ src, const int* __restrict__ dst,
    int* __restrict__ bkt_cur, uint2* __restrict__ ebuf, int n_edges, int nb) {
    __shared__ int hist[512];
    __shared__ int hbase[513];
    __shared__ int hcur[512];
    __shared__ uint2 sorted[EPW];
    int tid = threadIdx.x;
    int chunk0 = blockIdx.x * EPW;
    int cnt = min(EPW, n_edges - chunk0);
    hist[tid] = 0;
    __syncthreads();
    for (int i = tid; i < cnt; i += 512) atomicAdd(&hist[dst[chunk0 + i] >> NBSH], 1);
    __syncthreads();
    int v = hist[tid];
    hbase[tid] = v;
    __syncthreads();
    for (int off = 1; off < 512; off <<= 1) {
        int u = (tid >= off) ? hbase[tid - off] : 0;
        __syncthreads();
        hbase[tid] += u;
        __syncthreads();
    }
    int excl = hbase[tid] - v;
    __syncthreads();
    hbase[tid] = excl;
    hcur[tid] = excl;
    if (tid == 511) hbase[512] = excl + v;
    __syncthreads();
    for (int i = tid; i < cnt; i += 512) {
        int s = src[chunk0 + i];
        int d = dst[chunk0 + i];
        int p = atomicAdd(&hcur[d >> NBSH], 1);
        sorted[p] = make_uint2((unsigned)s, (unsigned)d);
    }
    __syncthreads();
    int cntb = hbase[tid + 1] - hbase[tid];
    int gb = 0;
    if (tid < nb && cntb > 0) gb = atomicAdd(&bkt_cur[tid], cntb);
    hist[tid] = gb;
    __syncthreads();
    for (int i = tid; i < cnt; i += 512) {
        uint2 ed = sorted[i];
        int b = (int)(ed.y >> NBSH);
        ebuf[hist[b] + (i - hbase[b])] = ed;
    }
}

// Fused: per-bucket degree count + local scan -> row_start + LDS-cursor scatter.
__global__ void sort_bucket(const uint2* __restrict__ ebuf, const int* __restrict__ bkt_base,
                            int* __restrict__ row_start, int* __restrict__ col,
                            int n_nodes, int n_edges) {
    __shared__ int hist[128];
    __shared__ int sc[128];
    __shared__ int hcur[128];
    int b = blockIdx.x, tid = threadIdx.x;
    int lo = b << NBSH;
    if (tid < 128) hist[tid] = 0;
    __syncthreads();
    int s = bkt_base[b], t = bkt_base[b + 1];
    for (int i = s + tid; i < t; i += 256) atomicAdd(&hist[(int)ebuf[i].y - lo], 1);
    __syncthreads();
    if (tid < 128) sc[tid] = hist[tid];
    __syncthreads();
    for (int off = 1; off < 128; off <<= 1) {
        int u = (tid < 128 && tid >= off) ? sc[tid - off] : 0;
        __syncthreads();
        if (tid < 128) sc[tid] += u;
        __syncthreads();
    }
    if (tid < 128) {
        int excl = sc[tid] - hist[tid];
        hcur[tid] = excl;
        int node = lo + tid;
        if (node < n_nodes) row_start[node] = s + excl;
    }
    if (b == 0 && tid == 0) row_start[n_nodes] = n_edges;
    __syncthreads();
    for (int i = s + tid; i < t; i += 256) {
        uint2 ed = ebuf[i];
        int p = atomicAdd(&hcur[(int)ed.y - lo], 1);
        col[s + p] = (int)ed.x;
    }
}

// -------- fused prep: convert_x + 3x build_bt + cat + bucket histogram ------
__device__ __forceinline__ void bt_body(const float* __restrict__ Wl,
                                        const float* __restrict__ Wr,
                                        unsigned short* __restrict__ Bt,
                                        int KA, int idx) {
    int KTOT = 2 * KA;
    if (idx >= 128 * KTOT) return;
    int n = idx / KTOT, k = idx % KTOT;
    float v = (k < KA) ? Wl[k * 128 + n] : Wr[(k - KA) * 128 + n];
    Bt[idx] = f2b(v);
}

__global__ void prep_all(const float* __restrict__ x, unsigned short* __restrict__ xb, int n4,
                         const float* __restrict__ Wl1, const float* __restrict__ Wr1,
                         unsigned short* __restrict__ Bt1,
                         const float* __restrict__ Wl2, const float* __restrict__ Wr2,
                         unsigned short* __restrict__ Bt2,
                         const float* __restrict__ Wl3, const float* __restrict__ Wr3,
                         unsigned short* __restrict__ Bt3,
                         const float* __restrict__ Wl_age, const float* __restrict__ Wl_sex,
                         const float* __restrict__ Wl_eth,
                         const float* __restrict__ Wr_age, const float* __restrict__ Wr_sex,
                         const float* __restrict__ Wr_eth,
                         const float* __restrict__ b_age, const float* __restrict__ b_sex,
                         const float* __restrict__ b_eth,
                         float* __restrict__ Wl_cat, float* __restrict__ Wr_cat,
                         float* __restrict__ b_cat,
                         const int* __restrict__ edge_dst, int n_edges,
                         int* __restrict__ bkt_hist) {
    __shared__ int lh[512];
    int tid = threadIdx.x;
    int nbx = (n4 + 255) / 256;       // convert_x blocks
    int b = blockIdx.x;
    if (b < nbx) {
        int t = b * 256 + tid;
        if (t < n4) {
            float4 v = reinterpret_cast<const float4*>(x)[t];
            uint2 o;
            o.x = (unsigned)f2b(v.x) | ((unsigned)f2b(v.y) << 16);
            o.y = (unsigned)f2b(v.z) | ((unsigned)f2b(v.w) << 16);
            reinterpret_cast<uint2*>(xb)[t] = o;
        }
        return;
    }
    b -= nbx;
    if (b < 64)  { bt_body(Wl1, Wr1, Bt1, 64,  b * 256 + tid); return; }
    b -= 64;
    if (b < 128) { bt_body(Wl2, Wr2, Bt2, 128, b * 256 + tid); return; }
    b -= 128;
    if (b < 128) { bt_body(Wl3, Wr3, Bt3, 128, b * 256 + tid); return; }
    b -= 128;
    if (b < 14) {   // cat: 14 blocks cover 128*28
        int idx = b * 256 + tid;
        if (idx < 128 * 28) {
            int k = idx / 28, j = idx % 28;
            float vl, vr;
            if (j < 21) {
                vl = Wl_age[k * 21 + j];
                vr = Wr_age[k * 21 + j];
            } else if (j < 23) {
                vl = Wl_sex[k * 2 + (j - 21)];
                vr = Wr_sex[k * 2 + (j - 21)];
            } else {
                vl = Wl_eth[k * 5 + (j - 23)];
                vr = Wr_eth[k * 5 + (j - 23)];
            }
            Wl_cat[idx] = vl;
            Wr_cat[idx] = vr;
        }
        if (idx < 28)
            b_cat[idx] = (idx < 21) ? b_age[idx] : (idx < 23) ? b_sex[idx - 21] : b_eth[idx - 23];
        return;
    }
    b -= 14;
    {   // 256 histogram blocks (bkt_hist pre-zeroed by memset before launch)
        for (int i = tid; i < 512; i += 256) lh[i] = 0;
        __syncthreads();
        for (int e = b * 256 + tid; e < n_edges; e += 256 * 256)
            atomicAdd(&lh[edge_dst[e] >> NBSH], 1);
        __syncthreads();
        for (int i = tid; i < 512; i += 256)
            if (lh[i]) atomicAdd(&bkt_hist[i], lh[i]);
    }
}

// ---------------- bf16 gather aggregation ----------------
__global__ void agg128_bf(const unsigned short* __restrict__ feat,
                          const int* __restrict__ row_start, const int* __restrict__ col,
                          unsigned short* __restrict__ mean, int n_nodes) {
    int wave = (blockIdx.x * blockDim.x + threadIdx.x) >> 6;
    int lane = threadIdx.x & 63;
    if (wave >= n_nodes) return;
    int s0 = row_start[wave];
    int deg = row_start[wave + 1] - s0;
    const unsigned* f2 = reinterpret_cast<const unsigned*>(feat);
    float a0 = 0.f, a1 = 0.f, b0 = 0.f, b1 = 0.f;
    float c0 = 0.f, c1 = 0.f, d0 = 0.f, d1 = 0.f;
    for (int base = 0; base < deg; base += 64) {
        int blk = min(64, deg - base);
        int cv = col[s0 + base + min(lane, blk - 1)];
        int i = 0;
        for (; i + 3 < blk; i += 4) {
            int e0 = __shfl(cv, i), e1 = __shfl(cv, i + 1);
            int e2 = __shfl(cv, i + 2), e3 = __shfl(cv, i + 3);
            unsigned u0 = f2[(size_t)e0 * 64 + lane];
            unsigned u1 = f2[(size_t)e1 * 64 + lane];
            unsigned u2 = f2[(size_t)e2 * 64 + lane];
            unsigned u3 = f2[(size_t)e3 * 64 + lane];
            a0 += b2f((unsigned short)(u0 & 0xffff)); a1 += b2f((unsigned short)(u0 >> 16));
            b0 += b2f((unsigned short)(u1 & 0xffff)); b1 += b2f((unsigned short)(u1 >> 16));
            c0 += b2f((unsigned short)(u2 & 0xffff)); c1 += b2f((unsigned short)(u2 >> 16));
            d0 += b2f((unsigned short)(u3 & 0xffff)); d1 += b2f((unsigned short)(u3 >> 16));
        }
        for (; i < blk; ++i) {
            int e0 = __shfl(cv, i);
            unsigned u0 = f2[(size_t)e0 * 64 + lane];
            a0 += b2f((unsigned short)(u0 & 0xffff)); a1 += b2f((unsigned short)(u0 >> 16));
        }
    }
    float inv = (deg > 0) ? 1.0f / (float)deg : 0.0f;
    float sA = (a0 + b0) + (c0 + d0);
    float sB = (a1 + b1) + (c1 + d1);
    unsigned o = (unsigned)f2b(sA * inv) | ((unsigned)f2b(sB * inv) << 16);
    reinterpret_cast<unsigned*>(mean)[(size_t)wave * 64 + lane] = o;
}

__global__ void agg64_bf(const unsigned short* __restrict__ feat,
                         const int* __restrict__ row_start, const int* __restrict__ col,
                         unsigned short* __restrict__ mean, int n_nodes) {
    int wave = (blockIdx.x * blockDim.x + threadIdx.x) >> 6;
    int lane = threadIdx.x & 63;
    if (wave >= n_nodes) return;
    int half = lane >> 5;
    int lp = lane & 31;
    int s0 = row_start[wave];
    int deg = row_start[wave + 1] - s0;
    const unsigned* f2 = reinterpret_cast<const unsigned*>(feat);
    float a0 = 0.f, a1 = 0.f, b0 = 0.f, b1 = 0.f;
    float c0 = 0.f, c1 = 0.f, d0 = 0.f, d1 = 0.f;
    for (int base = 0; base < deg; base += 64) {
        int blk = min(64, deg - base);
        int cv = col[s0 + base + min(lane, blk - 1)];
        int nfull = blk & ~7;
        for (int i = half * 4; i < nfull; i += 8) {
            int e0 = __shfl(cv, i), e1 = __shfl(cv, i + 1);
            int e2 = __shfl(cv, i + 2), e3 = __shfl(cv, i + 3);
            unsigned u0 = f2[(size_t)e0 * 32 + lp];
            unsigned u1 = f2[(size_t)e1 * 32 + lp];
            unsigned u2 = f2[(size_t)e2 * 32 + lp];
            unsigned u3 = f2[(size_t)e3 * 32 + lp];
            a0 += b2f((unsigned short)(u0 & 0xffff)); a1 += b2f((unsigned short)(u0 >> 16));
            b0 += b2f((unsigned short)(u1 & 0xffff)); b1 += b2f((unsigned short)(u1 >> 16));
            c0 += b2f((unsigned short)(u2 & 0xffff)); c1 += b2f((unsigned short)(u2 >> 16));
            d0 += b2f((unsigned short)(u3 & 0xffff)); d1 += b2f((unsigned short)(u3 >> 16));
        }
        int tstart = nfull + half * 4;
        int tend = min(blk, tstart + 4);
        for (int i = tstart; i < tend; ++i) {
            int e0 = __shfl(cv, i);
            unsigned u0 = f2[(size_t)e0 * 32 + lp];
            a0 += b2f((unsigned short)(u0 & 0xffff)); a1 += b2f((unsigned short)(u0 >> 16));
        }
    }
    float sA = (a0 + b0) + (c0 + d0);
    float sB = (a1 + b1) + (c1 + d1);
    sA += __shfl_down(sA, 32);
    sB += __shfl_down(sB, 32);
    if (half == 0) {
        float inv = (deg > 0) ? 1.0f / (float)deg : 0.0f;
        unsigned o = (unsigned)f2b(sA * inv) | ((unsigned)f2b(sB * inv) << 16);
        reinterpret_cast<unsigned*>(mean)[(size_t)wave * 32 + lp] = o;
    }
}

// ---------------- MFMA layer GEMM ----------------
template <int KTOT, int KA>
__global__ __launch_bounds__(256) void mfma_layer(
    const unsigned short* __restrict__ A0, const unsigned short* __restrict__ A1,
    const unsigned short* __restrict__ Bt, const float* __restrict__ bias,
    unsigned short* __restrict__ out, int n_nodes) {
    constexpr int KC = KTOT / 64;
    __shared__ __align__(16) unsigned short sA[64][72];
    __shared__ __align__(16) unsigned short sB[128][72];
    int node0 = blockIdx.x * 64;
    int tid = threadIdx.x;
    int w = tid >> 6, lane = tid & 63;
    f32x4 acc[8] = {};
    for (int kc = 0; kc < KC; ++kc) {
        const unsigned short* Asrc;
        int kbase, aw;
        if (kc * 64 < KA) { Asrc = A0; kbase = kc * 64; aw = KA; }
        else              { Asrc = A1; kbase = kc * 64 - KA; aw = KTOT - KA; }
        {
            int nd = tid >> 2, k16 = (tid & 3) * 16;
            uint4 v0 = {0, 0, 0, 0}, v1 = {0, 0, 0, 0};
            int gn = node0 + nd;
            if (gn < n_nodes) {
                const uint4* src = reinterpret_cast<const uint4*>(Asrc + (size_t)gn * aw + kbase + k16);
                v0 = src[0];
                v1 = src[1];
            }
            uint4* dst = reinterpret_cast<uint4*>(&sA[nd][k16]);
            dst[0] = v0;
            dst[1] = v1;
        }
        {
            int n = tid >> 1, k32 = (tid & 1) * 32;
            const uint4* src = reinterpret_cast<const uint4*>(Bt + (size_t)n * KTOT + kc * 64 + k32);
            uint4* dst = reinterpret_cast<uint4*>(&sB[n][k32]);
            dst[0] = src[0];
            dst[1] = src[1];
            dst[2] = src[2];
            dst[3] = src[3];
        }
        __syncthreads();
#pragma unroll
        for (int ks = 0; ks < 2; ++ks) {
            int kl = ks * 32 + (lane >> 4) * 8;
            bf16x8 af = *reinterpret_cast<const bf16x8*>(&sA[w * 16 + (lane & 15)][kl]);
#pragma unroll
            for (int t = 0; t < 8; ++t) {
                bf16x8 bfr = *reinterpret_cast<const bf16x8*>(&sB[t * 16 + (lane & 15)][kl]);
                acc[t] = __builtin_amdgcn_mfma_f32_16x16x32_bf16(af, bfr, acc[t], 0, 0, 0);
            }
        }
        __syncthreads();
    }
    int r0 = w * 16, cq = lane >> 4, cr = lane & 15;
#pragma unroll
    for (int t = 0; t < 8; ++t) {
        int colj = t * 16 + cr;
        float bv = bias[colj];
#pragma unroll
        for (int i = 0; i < 4; ++i) {
            int node = node0 + r0 + cq * 4 + i;
            if (node < n_nodes) {
                float v = fmaxf(acc[t][i] + bv, 0.0f);
                out[(size_t)node * 128 + colj] = f2b(v);
            }
        }
    }
}

// ---------------- heads ----------------
// R10 register-blocked LDS GEMM: p = h@Wl, q = h@Wr + b (fp32).
__global__ __launch_bounds__(256) void proj2_kernel(
    const unsigned short* __restrict__ h,
    const float* __restrict__ Wl_cat, const float* __restrict__ Wr_cat,
    const float* __restrict__ b_cat,
    float* __restrict__ p, float* __restrict__ q, int n_nodes) {
    __shared__ float sh[64][128];        // 32 KB
    __shared__ float swl[128 * 28];      // 14 KB
    __shared__ float swr[128 * 28];      // 14 KB
    int node0 = blockIdx.x * 64;
    int tid = threadIdx.x;
    for (int i = tid; i < 128 * 28; i += 256) {
        swl[i] = Wl_cat[i];
        swr[i] = Wr_cat[i];
    }
    for (int it = tid; it < 1024; it += 256) {
        int n = it >> 4, k8 = (it & 15) * 8;
        int node = node0 + n;
        if (node < n_nodes) {
            uint4 u = *reinterpret_cast<const uint4*>(h + (size_t)node * 128 + k8);
            sh[n][k8 + 0] = b2f((unsigned short)(u.x & 0xffff));
            sh[n][k8 + 1] = b2f((unsigned short)(u.x >> 16));
            sh[n][k8 + 2] = b2f((unsigned short)(u.y & 0xffff));
            sh[n][k8 + 3] = b2f((unsigned short)(u.y >> 16));
            sh[n][k8 + 4] = b2f((unsigned short)(u.z & 0xffff));
            sh[n][k8 + 5] = b2f((unsigned short)(u.z >> 16));
            sh[n][k8 + 6] = b2f((unsigned short)(u.w & 0xffff));
            sh[n][k8 + 7] = b2f((unsigned short)(u.w >> 16));
        } else {
            for (int z = 0; z < 8; ++z) sh[n][k8 + z] = 0.f;
        }
    }
    __syncthreads();
    int j = tid & 31, ng = tid >> 5;
    float accp[8] = {};
    float accq[8] = {};
    if (j < 28) {
        for (int k = 0; k < 128; k += 2) {
            float wl0 = swl[k * 28 + j],       wr0 = swr[k * 28 + j];
            float wl1 = swl[(k + 1) * 28 + j], wr1 = swr[(k + 1) * 28 + j];
#pragma unroll
            for (int i = 0; i < 8; ++i) {
                float2 hv = *reinterpret_cast<const float2*>(&sh[ng * 8 + i][k]);
                accp[i] += hv.x * wl0 + hv.y * wl1;
                accq[i] += hv.x * wr0 + hv.y * wr1;
            }
        }
    }
    float bj = (j < 28) ? b_cat[j] : 0.f;
#pragma unroll
    for (int i = 0; i < 8; ++i) {
        int node = node0 + ng * 8 + i;
        if (node < n_nodes) {
            p[(size_t)node * 32 + j] = (j < 28) ? accp[i] : 0.f;
            q[(size_t)node * 32 + j] = (j < 28) ? (accq[i] + bj) : 0.f;
        }
    }
}

// 32-lane group per node: gather-mean of p + q[node] -> scatter to outputs.
__global__ void head_final(const float* __restrict__ p, const float* __restrict__ q,
                           const int* __restrict__ row_start, const int* __restrict__ col,
                           float* __restrict__ age, float* __restrict__ sex,
                           float* __restrict__ eth, int n_nodes) {
    int node = (blockIdx.x * blockDim.x + threadIdx.x) >> 5;
    int lane = threadIdx.x & 63;
    int lp = lane & 31;
    int grpbase = lane & 32;
    if (node >= n_nodes) return;
    int s0 = row_start[node];
    int deg = row_start[node + 1] - s0;
    float a = 0.f, b = 0.f, c = 0.f, d = 0.f;
    for (int base = 0; base < deg; base += 32) {
        int blk = min(32, deg - base);
        int cv = col[s0 + base + min(lp, blk - 1)];
        int i = 0;
        for (; i + 3 < blk; i += 4) {
            int e0 = __shfl(cv, grpbase + i),     e1 = __shfl(cv, grpbase + i + 1);
            int e2 = __shfl(cv, grpbase + i + 2), e3 = __shfl(cv, grpbase + i + 3);
            a += p[(size_t)e0 * 32 + lp];
            b += p[(size_t)e1 * 32 + lp];
            c += p[(size_t)e2 * 32 + lp];
            d += p[(size_t)e3 * 32 + lp];
        }
        for (; i < blk; ++i) {
            int e0 = __shfl(cv, grpbase + i);
            a += p[(size_t)e0 * 32 + lp];
        }
    }
    float inv = (deg > 0) ? 1.0f / (float)deg : 0.0f;
    float out = ((a + b) + (c + d)) * inv + q[(size_t)node * 32 + lp];
    if (lp < 21)
        age[(size_t)node * 21 + lp] = out;
    else if (lp < 23)
        sex[(size_t)node * 2 + (lp - 21)] = out;
    else if (lp < 28)
        eth[(size_t)node * 5 + (lp - 23)] = out;
}

extern "C" void kernel_launch(void* const* d_in, const int* in_sizes, int n_in,
                              void* d_out, int out_size, void* d_ws, size_t ws_size,
                              hipStream_t stream) {
    const float* x        = (const float*)d_in[0];
    const int*   edge_src = (const int*)d_in[1];
    const int*   edge_dst = (const int*)d_in[2];
    const float* Wl_1 = (const float*)d_in[3];
    const float* Wr_1 = (const float*)d_in[4];
    const float* b_1  = (const float*)d_in[5];
    const float* Wl_2 = (const float*)d_in[6];
    const float* Wr_2 = (const float*)d_in[7];
    const float* b_2  = (const float*)d_in[8];
    const float* Wl_3 = (const float*)d_in[9];
    const float* Wr_3 = (const float*)d_in[10];
    const float* b_3  = (const float*)d_in[11];
    const float* Wl_age = (const float*)d_in[12];
    const float* Wr_age = (const float*)d_in[13];
    const float* b_age  = (const float*)d_in[14];
    const float* Wl_sex = (const float*)d_in[15];
    const float* Wr_sex = (const float*)d_in[16];
    const float* b_sex  = (const float*)d_in[17];
    const float* Wl_eth = (const float*)d_in[18];
    const float* Wr_eth = (const float*)d_in[19];
    const float* b_eth  = (const float*)d_in[20];

    const int n_nodes = in_sizes[0] / 64;   // 50000
    const int n_edges = in_sizes[1];        // 800000

    // ---- workspace layout (R10) ----
    char* ws = (char*)d_ws;
    int*            row_start = (int*)(ws + 200192);             // 200192
    int*            col       = (int*)(ws + 600576);             // 3200256
    unsigned short* Bt1       = (unsigned short*)(ws + 3800832); // 32768
    unsigned short* Bt2       = (unsigned short*)(ws + 3833600); // 65536
    unsigned short* Bt3       = (unsigned short*)(ws + 3899136); // 65536
    float*          Wl_cat    = (float*)(ws + 3964672);          // 14336
    float*          Wr_cat    = (float*)(ws + 3979008);          // 14336
    float*          b_cat     = (float*)(ws + 3993344);          // 256
    unsigned short* xb        = (unsigned short*)(ws + 3993600); // 6400256
    unsigned short* h_bf      = (unsigned short*)(ws + 10393856);// 12800256
    unsigned short* mean_bf   = (unsigned short*)(ws + 23194112);// 12800256
    float*          p         = (float*)(ws + 35994368);         // 6400256  (head phase)
    float*          q         = (float*)(ws + 42394624);         // 6400256  (head phase)
    // CSR-build-phase aliases (p / q not live yet):
    uint2*          ebuf      = (uint2*)p;                       // 6.4 MB
    int*            bkt_hist  = (int*)q;                         // 512 ints
    int*            bkt_base  = bkt_hist + 512;                  // 513 ints
    int*            bkt_cur   = bkt_hist + 1032;                 // 512 ints

    float* out_age = (float*)d_out;
    float* out_sex = out_age + (size_t)n_nodes * 21;
    float* out_eth = out_sex + (size_t)n_nodes * 2;

    const int nb      = (n_nodes + 127) >> NBSH;          // 391 buckets
    const int nchunks = (n_edges + EPW - 1) / EPW;        // 196
    const int n4      = n_nodes * 64 / 4;                 // 800000

    // ---- zero bucket histogram, then fused prep (incl. histogram blocks) ----
    hipMemsetAsync(bkt_hist, 0, 512 * sizeof(int), stream);
    {
        int grid = (n4 + 255) / 256 + 64 + 128 + 128 + 14 + 256;
        prep_all<<<grid, 256, 0, stream>>>(
            x, xb, n4, Wl_1, Wr_1, Bt1, Wl_2, Wr_2, Bt2, Wl_3, Wr_3, Bt3,
            Wl_age, Wl_sex, Wl_eth, Wr_age, Wr_sex, Wr_eth, b_age, b_sex, b_eth,
            Wl_cat, Wr_cat, b_cat, edge_dst, n_edges, bkt_hist);
    }

    // ---- CSR build (bucketed, locality-aware) ----
    scan_buckets<<<1, 512, 0, stream>>>(bkt_hist, bkt_base, bkt_cur, nb, n_edges);
    bin_edges_lds<<<nchunks, 512, 0, stream>>>(edge_src, edge_dst, bkt_cur, ebuf, n_edges, nb);
    sort_bucket<<<nb, 256, 0, stream>>>(ebuf, bkt_base, row_start, col, n_nodes, n_edges);

    const int agg_grid  = (n_nodes * 64 + 255) / 256;
    const int gemm_grid = (n_nodes + 63) / 64;

    // ---- Layer 1: A = [mean(x)(64) | x(64)] ----
    agg64_bf<<<agg_grid, 256, 0, stream>>>(xb, row_start, col, mean_bf, n_nodes);
    mfma_layer<128, 64><<<gemm_grid, 256, 0, stream>>>(mean_bf, xb, Bt1, b_1, h_bf, n_nodes);

    // ---- Layer 2 ----
    agg128_bf<<<agg_grid, 256, 0, stream>>>(h_bf, row_start, col, mean_bf, n_nodes);
    mfma_layer<256, 128><<<gemm_grid, 256, 0, stream>>>(mean_bf, h_bf, Bt2, b_2, h_bf, n_nodes);

    // ---- Layer 3 ----
    agg128_bf<<<agg_grid, 256, 0, stream>>>(h_bf, row_start, col, mean_bf, n_nodes);
    mfma_layer<256, 128><<<gemm_grid, 256, 0, stream>>>(mean_bf, h_bf, Bt3, b_3, h_bf, n_nodes);

    // ---- Heads: p = h@Wl, q = h@Wr+b, then mean(p)+q -> scatter ----
    proj2_kernel<<<(n_nodes + 63) / 64, 256, 0, stream>>>(h_bf, Wl_cat, Wr_cat, b_cat, p, q, n_nodes);
    head_final<<<(n_nodes * 32 + 255) / 256, 256, 0, stream>>>(
        p, q, row_start, col, out_age, out_sex, out_eth, n_nodes);
}